// Round 11
// baseline (123.108 us; speedup 1.0000x reference)
//
#include <hip/hip_runtime.h>
#include <hip/hip_bf16.h>

typedef __attribute__((ext_vector_type(8))) __bf16 bf16x8;
typedef __attribute__((ext_vector_type(4))) float f32x4;

namespace {

constexpr int L = 2048;      // query length (== S)
constexpr int E = 64;        // embed dim == value dim
constexpr int NHEAD = 16;    // B*H reinterpreted heads
constexpr float SCALE = 0.125f;   // 1/sqrt(64)
constexpr float LOG2E = 1.44269504f;
constexpr float TWO_LOG2E = 2.88539008f;

// workspace layout (bytes)
constexpr size_t KN_OFF = 4096;                               // f32 [16][2048]  (-log2e*|k|^2)
constexpr size_t KB_OFF = KN_OFF + (size_t)NHEAD * L * 4;     // bf16 [16][2048][64]
constexpr size_t VT_OFF = KB_OFF + (size_t)NHEAD * L * E * 2; // bf16 [16][64][2048]
constexpr size_t P_OFF  = VT_OFF + (size_t)NHEAD * E * L * 2; // f32 [4][16][2048][64] partials
constexpr size_t D_OFF  = P_OFF + (size_t)4 * NHEAD * L * E * 4; // f32 [4][16][2048]

// XOR swizzle within a 128-byte LDS row (verified low-conflict rounds 5-8)
__device__ __forceinline__ int swz(int row, int byte_in_row) {
  const int f = (row & 3) | (((row >> 3) & 1) << 2);
  return row * 128 + (byte_in_row ^ (f << 4));
}

__device__ __forceinline__ unsigned pack_bf16(float a, float b) {
  union { __bf16 h[2]; unsigned u; } p;
  p.h[0] = (__bf16)a; p.h[1] = (__bf16)b;
  return p.u;
}

__device__ __forceinline__ void cvt_row16(const float4* src, float& pn,
                                          bf16x8& w0, bf16x8& w1) {
  float4 a = src[0], c = src[1];
  pn += a.x*a.x + a.y*a.y + a.z*a.z + a.w*a.w;
  pn += c.x*c.x + c.y*c.y + c.z*c.z + c.w*c.w;
  w0[0]=(__bf16)a.x; w0[1]=(__bf16)a.y; w0[2]=(__bf16)a.z; w0[3]=(__bf16)a.w;
  w0[4]=(__bf16)c.x; w0[5]=(__bf16)c.y; w0[6]=(__bf16)c.z; w0[7]=(__bf16)c.w;
  float4 d = src[2], e = src[3];
  pn += d.x*d.x + d.y*d.y + d.z*d.z + d.w*d.w;
  pn += e.x*e.x + e.y*e.y + e.z*e.z + e.w*e.w;
  w1[0]=(__bf16)d.x; w1[1]=(__bf16)d.y; w1[2]=(__bf16)d.z; w1[3]=(__bf16)d.w;
  w1[4]=(__bf16)e.x; w1[5]=(__bf16)e.y; w1[6]=(__bf16)e.z; w1[7]=(__bf16)e.w;
}

// merged prep: blocks [0,512) convert K -> bf16 + scaled norms; [512,1024) transpose V
__global__ __launch_bounds__(256)
void prep(const float* __restrict__ Kg, const float* __restrict__ Vg,
          __bf16* __restrict__ Kb, float* __restrict__ kn,
          __bf16* __restrict__ Vt) {
  __shared__ float Vs[64][65];
  const int t = threadIdx.x;
  if (blockIdx.x < 512) {
    const int row = blockIdx.x * 64 + (t >> 2);
    const int seg = t & 3;
    const float4* src = reinterpret_cast<const float4*>(
        Kg + (size_t)row * E + seg * 16);
    float pn = 0.f; bf16x8 w0, w1;
    cvt_row16(src, pn, w0, w1);
    __bf16* dst = Kb + (size_t)row * E + seg * 16;
    *reinterpret_cast<bf16x8*>(dst)     = w0;
    *reinterpret_cast<bf16x8*>(dst + 8) = w1;
    pn += __shfl_xor(pn, 1);
    pn += __shfl_xor(pn, 2);
    if (seg == 0) kn[row] = -LOG2E * pn;      // pre-scaled
  } else {
    const int bb = blockIdx.x - 512;
    const int n  = bb >> 5;    // head 0..15
    const int st = bb & 31;    // s-tile of 64
    const int b = n >> 3, h = n & 7;
    {
      const int srow = t >> 2, seg = t & 3;
      const float4* src = reinterpret_cast<const float4*>(
          Vg + ((size_t)b * L + st * 64 + srow) * 512 + h * 64 + seg * 16);
      #pragma unroll
      for (int jj = 0; jj < 4; ++jj) {
        float4 a = src[jj];
        Vs[srow][seg*16 + jj*4 + 0] = a.x;
        Vs[srow][seg*16 + jj*4 + 1] = a.y;
        Vs[srow][seg*16 + jj*4 + 2] = a.z;
        Vs[srow][seg*16 + jj*4 + 3] = a.w;
      }
    }
    __syncthreads();
    {
      const int d = t >> 2, sg = t & 3;
      bf16x8 o0, o1;
      #pragma unroll
      for (int i = 0; i < 8; ++i) o0[i] = (__bf16)Vs[sg*16 + i][d];
      #pragma unroll
      for (int i = 0; i < 8; ++i) o1[i] = (__bf16)Vs[sg*16 + 8 + i][d];
      __bf16* dst = Vt + (size_t)n * (E * L) + (size_t)d * L + st * 64 + sg * 16;
      *reinterpret_cast<bf16x8*>(dst)     = o0;
      *reinterpret_cast<bf16x8*>(dst + 8) = o1;
    }
  }
}

// ---- main attention: 2048 blocks x 4 waves; K in LDS (8KB), V direct from L2.
// Block = (head n, l-tile lt, slice j); handles chunks c == j (mod 4), c <= lt.
// Writes f32 partial O and den; merge kernel combines the 4 slices.
// Mapping: CU-group w gets tiles {w, 31-w} x all 4 slices = exactly 33 units.
__global__ __launch_bounds__(256, 8)
void degr_attn(const float* __restrict__ Qg, const __bf16* __restrict__ Kb,
               const __bf16* __restrict__ Vt, const float* __restrict__ kng,
               float* __restrict__ Pp, float* __restrict__ Dp) {
  __shared__ char smem[8192];    // K tile, swizzled, single-buffered

  const int id = blockIdx.x;
  const int n  = id & 15;                       // 2 heads per XCD (id%8 XCD rr)
  const int v  = id >> 4;
  const int w  = v & 15, k = v >> 4;
  const int lt = (k < 4) ? w : (31 - w);
  const int j  = k & 3;
  const int l0 = lt * 64;

  const int t = threadIdx.x;
  const int w4 = t >> 6;                        // wave 0..3
  const int lane = t & 63, lg = lane >> 4, lr = lane & 15;

  f32x4 oacc[4];
  #pragma unroll
  for (int i = 0; i < 4; ++i) oacc[i] = (f32x4){0.f, 0.f, 0.f, 0.f};
  float den = 0.f;

  const int l_glob = l0 + 16 * w4 + lr;

  if (j <= lt) {
    const float*  Qh  = Qg  + (size_t)n * (L * E);
    const __bf16* Kh  = Kb  + (size_t)n * (L * E);
    const __bf16* Vh  = Vt  + (size_t)n * (E * L);
    const float*  knh = kng + (size_t)n * L;

    // ---- Q fragments (f32 -> bf16 in regs) + lane-local qn ----
    bf16x8 qf0, qf1;
    float qnL;
    {
      const float* qp = Qh + (size_t)l_glob * E + 8 * lg;
      float4 a = *reinterpret_cast<const float4*>(qp);
      float4 d = *reinterpret_cast<const float4*>(qp + 4);
      float4 a2 = *reinterpret_cast<const float4*>(qp + 32);
      float4 d2v = *reinterpret_cast<const float4*>(qp + 36);
      float pn = 0.f;
      #pragma unroll
      for (int i = 0; i < 4; ++i) {
        float v0 = (i==0)?a.x:(i==1)?a.y:(i==2)?a.z:a.w;
        float v1 = (i==0)?d.x:(i==1)?d.y:(i==2)?d.z:d.w;
        float v2 = (i==0)?a2.x:(i==1)?a2.y:(i==2)?a2.z:a2.w;
        float v3 = (i==0)?d2v.x:(i==1)?d2v.y:(i==2)?d2v.z:d2v.w;
        qf0[i]   = (__bf16)v0;  qf0[i+4] = (__bf16)v1;
        qf1[i]   = (__bf16)v2;  qf1[i+4] = (__bf16)v3;
        float f;
        f = (float)qf0[i];   pn += f*f;
        f = (float)qf0[i+4]; pn += f*f;
        f = (float)qf1[i];   pn += f*f;
        f = (float)qf1[i+4]; pn += f*f;
      }
      pn += __shfl_xor(pn, 16);
      pn += __shfl_xor(pn, 32);
      qnL = -LOG2E * pn;
    }

    // ---- precomputed LDS offsets (K only) ----
    const int srow = t >> 2;
    const int scol = (t & 3) * 2;
    const int wk0 = swz(srow, scol*16);
    const int wk1 = swz(srow, scol*16 + 16);
    int koffL[4], koffH[4];
    #pragma unroll
    for (int hx = 0; hx < 4; ++hx) {
      const int krow = 32*(hx>>1) + 8*(lr>>2) + 4*(hx&1) + (lr&3);
      koffL[hx] = swz(krow, lg*16);
      koffH[hx] = swz(krow, 64 + lg*16);
    }

    bf16x8 kr0, kr1;
    auto loadK = [&](int c) {
      const __bf16* kp = Kh + (size_t)(c * 64 + srow) * E + scol * 8;
      kr0 = *reinterpret_cast<const bf16x8*>(kp);
      kr1 = *reinterpret_cast<const bf16x8*>(kp + 8);
    };
    auto writeK = [&]() {
      *reinterpret_cast<bf16x8*>(smem + wk0) = kr0;
      *reinterpret_cast<bf16x8*>(smem + wk1) = kr1;
    };

    auto compute = [&](int c, bool MASK) {
      const int s_base = c * 64;
      float4 kn4[4];
      kn4[0] = *reinterpret_cast<const float4*>(knh + s_base + 8*lg);
      kn4[1] = *reinterpret_cast<const float4*>(knh + s_base + 8*lg + 4);
      kn4[2] = *reinterpret_cast<const float4*>(knh + s_base + 32 + 8*lg);
      kn4[3] = *reinterpret_cast<const float4*>(knh + s_base + 36 + 8*lg);

      __builtin_amdgcn_s_setprio(1);
      unsigned up[4][2];
      #pragma unroll
      for (int hx = 0; hx < 4; ++hx) {
        const bf16x8 kf0 = *reinterpret_cast<const bf16x8*>(smem + koffL[hx]);
        const bf16x8 kf1 = *reinterpret_cast<const bf16x8*>(smem + koffH[hx]);
        f32x4 acc = (f32x4){0.f, 0.f, 0.f, 0.f};
        acc = __builtin_amdgcn_mfma_f32_16x16x32_bf16(kf0, qf0, acc, 0, 0, 0);
        acc = __builtin_amdgcn_mfma_f32_16x16x32_bf16(kf1, qf1, acc, 0, 0, 0);
        float wv4[4];
        #pragma unroll
        for (int r = 0; r < 4; ++r) {
          const float knv = (r==0)?kn4[hx].x:(r==1)?kn4[hx].y:(r==2)?kn4[hx].z:kn4[hx].w;
          float arg = fminf(fmaf(TWO_LOG2E, acc[r], qnL + knv), 0.f);
          float e1  = exp2f(arg);                     // e^{-d2}
          float y   = fmaf(-SCALE, e1, SCALE);        // in [0, 0.125]
          float tt  = fmaf(0.5f, y, 1.0f);
          float wv  = fmaf(y, tt, 1.0f);              // exp(y) 2nd-order poly
          if (MASK) {
            const int sof = 32*(hx>>1) + 8*lg + 4*(hx&1);
            wv = (s_base + sof + r <= l_glob) ? wv : 0.f;
          }
          den += wv;
          wv4[r] = wv;
        }
        up[hx][0] = pack_bf16(wv4[0], wv4[1]);
        up[hx][1] = pack_bf16(wv4[2], wv4[3]);
      }
      // ---- PV: P lane-local; V fragments direct from global (L2-resident) ----
      #pragma unroll
      for (int sc = 0; sc < 2; ++sc) {
        union { unsigned u[4]; bf16x8 vv; } pb;
        pb.u[0] = up[2*sc][0];
        pb.u[1] = up[2*sc][1];
        pb.u[2] = up[2*sc+1][0];
        pb.u[3] = up[2*sc+1][1];
        const bf16x8 pf = pb.vv;
        #pragma unroll
        for (int dsb = 0; dsb < 4; ++dsb) {
          const __bf16* vp = Vh + (size_t)(dsb*16 + lr) * L + s_base + sc*32 + lg*8;
          const bf16x8 vf = *reinterpret_cast<const bf16x8*>(vp);
          oacc[dsb] = __builtin_amdgcn_mfma_f32_16x16x32_bf16(pf, vf, oacc[dsb], 0, 0, 0);
        }
      }
      __builtin_amdgcn_s_setprio(0);
    };

    const int n_it = ((lt - j) >> 2) + 1;
    loadK(j);
    writeK();
    __syncthreads();
    for (int i = 0; i < n_it; ++i) {
      const int c = 4 * i + j;
      const bool more = (i + 1 < n_it);
      if (more) loadK(c + 4);              // prefetch to regs
      compute(c, c == lt);
      if (more) {
        __syncthreads();                   // all waves done reading
        writeK();
        __syncthreads();                   // staged data visible
      }
    }
  }

  // ---- den: reduce over lg (per l = lr) ----
  den += __shfl_xor(den, 16);
  den += __shfl_xor(den, 32);

  // ---- write partials (all blocks, including empty slices -> zeros) ----
  {
    float* pb = Pp + ((size_t)(j * 16 + n) * L + (l0 + 16 * w4)) * 64;
    #pragma unroll
    for (int r = 0; r < 4; ++r) {
      float* prow = pb + (size_t)(4*lg + r) * 64;
      #pragma unroll
      for (int dsb = 0; dsb < 4; ++dsb)
        prow[dsb*16 + lr] = oacc[dsb][r];
    }
    if (lane < 16)
      Dp[(size_t)(j * 16 + n) * L + l0 + 16 * w4 + lr] = den;
  }
}

// ---- merge: O = (sum_j P_j) / (sum_j den_j), normalized, final layout ----
__global__ __launch_bounds__(256)
void merge(const float* __restrict__ Pp, const float* __restrict__ Dp,
           float* __restrict__ Og) {
  const int gid = blockIdx.x * 256 + threadIdx.x;   // 0 .. 524287 (float4 units)
  const int nq = gid >> 4, d4 = gid & 15;
  const int n = nq >> 11, q = nq & 2047;
  const float4* P4 = reinterpret_cast<const float4*>(Pp);
  float sx = 0.f, sy = 0.f, sz = 0.f, sw = 0.f, den = 0.f;
  #pragma unroll
  for (int jj = 0; jj < 4; ++jj) {
    const float4 p = P4[((size_t)(jj << 15) + nq) * 16 + d4];
    sx += p.x; sy += p.y; sz += p.z; sw += p.w;
    den += Dp[(size_t)(jj << 15) + nq];
  }
  const float inv = 1.0f / den;
  float4 o; o.x = sx * inv; o.y = sy * inv; o.z = sz * inv; o.w = sw * inv;
  float* op = Og + ((size_t)(n >> 3) * L + q) * 512 + (n & 7) * 64 + d4 * 4;
  *reinterpret_cast<float4*>(op) = o;
}

} // namespace

extern "C" void kernel_launch(void* const* d_in, const int* in_sizes, int n_in,
                              void* d_out, int out_size, void* d_ws, size_t ws_size,
                              hipStream_t stream) {
  (void)in_sizes; (void)n_in; (void)out_size; (void)ws_size;
  const float* q = (const float*)d_in[0];
  const float* k = (const float*)d_in[1];
  const float* v = (const float*)d_in[2];
  float*       o = (float*)d_out;

  char* ws = (char*)d_ws;
  float*  kn = (float*)(ws + KN_OFF);
  __bf16* Kb = (__bf16*)(ws + KB_OFF);
  __bf16* Vt = (__bf16*)(ws + VT_OFF);
  float*  Pp = (float*)(ws + P_OFF);
  float*  Dp = (float*)(ws + D_OFF);

  prep<<<dim3(1024), dim3(256), 0, stream>>>(k, v, Kb, kn, Vt);
  degr_attn<<<dim3(2048), dim3(256), 0, stream>>>(q, Kb, Vt, kn, Pp, Dp);
  merge<<<dim3(2048), dim3(256), 0, stream>>>(Pp, Dp, o);
}

// Round 12
// 69.645 us; speedup vs baseline: 1.7677x; 1.7677x over previous
//
#include <hip/hip_runtime.h>
#include <hip/hip_bf16.h>

typedef __attribute__((ext_vector_type(8))) __bf16 bf16x8;
typedef __attribute__((ext_vector_type(4))) float f32x4;

namespace {

constexpr int L = 2048;      // query length (== S)
constexpr int E = 64;        // embed dim == value dim
constexpr int NHEAD = 16;    // B*H reinterpreted heads
constexpr float SCALE = 0.125f;   // 1/sqrt(64)
constexpr float LOG2E = 1.44269504f;
constexpr float TWO_LOG2E = 2.88539008f;

// workspace layout (bytes)
constexpr size_t KN_OFF = 4096;                               // f32 [16][2048]  (-log2e*|k|^2)
constexpr size_t KB_OFF = KN_OFF + (size_t)NHEAD * L * 4;     // bf16 [16][2048][64]
constexpr size_t VT_OFF = KB_OFF + (size_t)NHEAD * L * E * 2; // bf16 [16][64][2048]
constexpr size_t P_OFF  = VT_OFF + (size_t)NHEAD * E * L * 2; // f32 [4][16][2048][64] partials
constexpr size_t D_OFF  = P_OFF + (size_t)4 * NHEAD * L * E * 4; // f32 [4][16][2048]

// XOR swizzle within a 128-byte LDS row (verified low-conflict rounds 5-8)
__device__ __forceinline__ int swz(int row, int byte_in_row) {
  const int f = (row & 3) | (((row >> 3) & 1) << 2);
  return row * 128 + (byte_in_row ^ (f << 4));
}

__device__ __forceinline__ unsigned pack_bf16(float a, float b) {
  union { __bf16 h[2]; unsigned u; } p;
  p.h[0] = (__bf16)a; p.h[1] = (__bf16)b;
  return p.u;
}

__device__ __forceinline__ void cvt_row16(const float4* src, float& pn,
                                          bf16x8& w0, bf16x8& w1) {
  float4 a = src[0], c = src[1];
  pn += a.x*a.x + a.y*a.y + a.z*a.z + a.w*a.w;
  pn += c.x*c.x + c.y*c.y + c.z*c.z + c.w*c.w;
  w0[0]=(__bf16)a.x; w0[1]=(__bf16)a.y; w0[2]=(__bf16)a.z; w0[3]=(__bf16)a.w;
  w0[4]=(__bf16)c.x; w0[5]=(__bf16)c.y; w0[6]=(__bf16)c.z; w0[7]=(__bf16)c.w;
  float4 d = src[2], e = src[3];
  pn += d.x*d.x + d.y*d.y + d.z*d.z + d.w*d.w;
  pn += e.x*e.x + e.y*e.y + e.z*e.z + e.w*e.w;
  w1[0]=(__bf16)d.x; w1[1]=(__bf16)d.y; w1[2]=(__bf16)d.z; w1[3]=(__bf16)d.w;
  w1[4]=(__bf16)e.x; w1[5]=(__bf16)e.y; w1[6]=(__bf16)e.z; w1[7]=(__bf16)e.w;
}

// merged prep: blocks [0,512) convert K -> bf16 + scaled norms; [512,1024) transpose V
__global__ __launch_bounds__(256)
void prep(const float* __restrict__ Kg, const float* __restrict__ Vg,
          __bf16* __restrict__ Kb, float* __restrict__ kn,
          __bf16* __restrict__ Vt) {
  __shared__ float Vs[64][65];
  const int t = threadIdx.x;
  if (blockIdx.x < 512) {
    const int row = blockIdx.x * 64 + (t >> 2);
    const int seg = t & 3;
    const float4* src = reinterpret_cast<const float4*>(
        Kg + (size_t)row * E + seg * 16);
    float pn = 0.f; bf16x8 w0, w1;
    cvt_row16(src, pn, w0, w1);
    __bf16* dst = Kb + (size_t)row * E + seg * 16;
    *reinterpret_cast<bf16x8*>(dst)     = w0;
    *reinterpret_cast<bf16x8*>(dst + 8) = w1;
    pn += __shfl_xor(pn, 1);
    pn += __shfl_xor(pn, 2);
    if (seg == 0) kn[row] = -LOG2E * pn;      // pre-scaled
  } else {
    const int bb = blockIdx.x - 512;
    const int n  = bb >> 5;    // head 0..15
    const int st = bb & 31;    // s-tile of 64
    const int b = n >> 3, h = n & 7;
    {
      const int srow = t >> 2, seg = t & 3;
      const float4* src = reinterpret_cast<const float4*>(
          Vg + ((size_t)b * L + st * 64 + srow) * 512 + h * 64 + seg * 16);
      #pragma unroll
      for (int jj = 0; jj < 4; ++jj) {
        float4 a = src[jj];
        Vs[srow][seg*16 + jj*4 + 0] = a.x;
        Vs[srow][seg*16 + jj*4 + 1] = a.y;
        Vs[srow][seg*16 + jj*4 + 2] = a.z;
        Vs[srow][seg*16 + jj*4 + 3] = a.w;
      }
    }
    __syncthreads();
    {
      const int d = t >> 2, sg = t & 3;
      bf16x8 o0, o1;
      #pragma unroll
      for (int i = 0; i < 8; ++i) o0[i] = (__bf16)Vs[sg*16 + i][d];
      #pragma unroll
      for (int i = 0; i < 8; ++i) o1[i] = (__bf16)Vs[sg*16 + 8 + i][d];
      __bf16* dst = Vt + (size_t)n * (E * L) + (size_t)d * L + st * 64 + sg * 16;
      *reinterpret_cast<bf16x8*>(dst)     = o0;
      *reinterpret_cast<bf16x8*>(dst + 8) = o1;
    }
  }
}

// ---- main attention: 2048 blocks x 4 waves; K in LDS (8KB), V direct from L2.
// Block = (head n, l-tile lt, slice j); handles chunks c == j (mod 4), c <= lt.
// Writes f32 partial O and den; merge kernel combines the 4 slices.
// NOTE: launch_bounds min-waves MUST stay <= 4: the ~90-VGPR state spills at
// the 64-VGPR cap that min-waves=8 implies (measured rounds 10/11: 260MB spill).
__global__ __launch_bounds__(256, 4)
void degr_attn(const float* __restrict__ Qg, const __bf16* __restrict__ Kb,
               const __bf16* __restrict__ Vt, const float* __restrict__ kng,
               float* __restrict__ Pp, float* __restrict__ Dp) {
  __shared__ char smem[8192];    // K tile, swizzled, single-buffered

  const int id = blockIdx.x;
  const int n  = id & 15;                       // 2 heads per XCD (id%8 XCD rr)
  const int v  = id >> 4;
  const int w  = v & 15, k = v >> 4;
  const int lt = (k < 4) ? w : (31 - w);
  const int j  = k & 3;
  const int l0 = lt * 64;

  const int t = threadIdx.x;
  const int w4 = t >> 6;                        // wave 0..3
  const int lane = t & 63, lg = lane >> 4, lr = lane & 15;

  f32x4 oacc[4];
  #pragma unroll
  for (int i = 0; i < 4; ++i) oacc[i] = (f32x4){0.f, 0.f, 0.f, 0.f};
  float den = 0.f;

  const int l_glob = l0 + 16 * w4 + lr;

  if (j <= lt) {
    const float*  Qh  = Qg  + (size_t)n * (L * E);
    const __bf16* Kh  = Kb  + (size_t)n * (L * E);
    const __bf16* Vh  = Vt  + (size_t)n * (E * L);
    const float*  knh = kng + (size_t)n * L;

    // ---- Q fragments (f32 -> bf16 in regs) + lane-local qn ----
    bf16x8 qf0, qf1;
    float qnL;
    {
      const float* qp = Qh + (size_t)l_glob * E + 8 * lg;
      float4 a = *reinterpret_cast<const float4*>(qp);
      float4 d = *reinterpret_cast<const float4*>(qp + 4);
      float4 a2 = *reinterpret_cast<const float4*>(qp + 32);
      float4 d2v = *reinterpret_cast<const float4*>(qp + 36);
      float pn = 0.f;
      #pragma unroll
      for (int i = 0; i < 4; ++i) {
        float v0 = (i==0)?a.x:(i==1)?a.y:(i==2)?a.z:a.w;
        float v1 = (i==0)?d.x:(i==1)?d.y:(i==2)?d.z:d.w;
        float v2 = (i==0)?a2.x:(i==1)?a2.y:(i==2)?a2.z:a2.w;
        float v3 = (i==0)?d2v.x:(i==1)?d2v.y:(i==2)?d2v.z:d2v.w;
        qf0[i]   = (__bf16)v0;  qf0[i+4] = (__bf16)v1;
        qf1[i]   = (__bf16)v2;  qf1[i+4] = (__bf16)v3;
        float f;
        f = (float)qf0[i];   pn += f*f;
        f = (float)qf0[i+4]; pn += f*f;
        f = (float)qf1[i];   pn += f*f;
        f = (float)qf1[i+4]; pn += f*f;
      }
      pn += __shfl_xor(pn, 16);
      pn += __shfl_xor(pn, 32);
      qnL = -LOG2E * pn;
    }

    // ---- precomputed LDS offsets (K only) ----
    const int srow = t >> 2;
    const int scol = (t & 3) * 2;
    const int wk0 = swz(srow, scol*16);
    const int wk1 = swz(srow, scol*16 + 16);
    int koffL[4], koffH[4];
    #pragma unroll
    for (int hx = 0; hx < 4; ++hx) {
      const int krow = 32*(hx>>1) + 8*(lr>>2) + 4*(hx&1) + (lr&3);
      koffL[hx] = swz(krow, lg*16);
      koffH[hx] = swz(krow, 64 + lg*16);
    }

    bf16x8 kr0, kr1;
    auto loadK = [&](int c) {
      const __bf16* kp = Kh + (size_t)(c * 64 + srow) * E + scol * 8;
      kr0 = *reinterpret_cast<const bf16x8*>(kp);
      kr1 = *reinterpret_cast<const bf16x8*>(kp + 8);
    };
    auto writeK = [&]() {
      *reinterpret_cast<bf16x8*>(smem + wk0) = kr0;
      *reinterpret_cast<bf16x8*>(smem + wk1) = kr1;
    };

    auto compute = [&](int c, bool MASK) {
      const int s_base = c * 64;
      float4 kn4[4];
      kn4[0] = *reinterpret_cast<const float4*>(knh + s_base + 8*lg);
      kn4[1] = *reinterpret_cast<const float4*>(knh + s_base + 8*lg + 4);
      kn4[2] = *reinterpret_cast<const float4*>(knh + s_base + 32 + 8*lg);
      kn4[3] = *reinterpret_cast<const float4*>(knh + s_base + 36 + 8*lg);

      __builtin_amdgcn_s_setprio(1);
      unsigned up[4][2];
      #pragma unroll
      for (int hx = 0; hx < 4; ++hx) {
        const bf16x8 kf0 = *reinterpret_cast<const bf16x8*>(smem + koffL[hx]);
        const bf16x8 kf1 = *reinterpret_cast<const bf16x8*>(smem + koffH[hx]);
        f32x4 acc = (f32x4){0.f, 0.f, 0.f, 0.f};
        acc = __builtin_amdgcn_mfma_f32_16x16x32_bf16(kf0, qf0, acc, 0, 0, 0);
        acc = __builtin_amdgcn_mfma_f32_16x16x32_bf16(kf1, qf1, acc, 0, 0, 0);
        float wv4[4];
        #pragma unroll
        for (int r = 0; r < 4; ++r) {
          const float knv = (r==0)?kn4[hx].x:(r==1)?kn4[hx].y:(r==2)?kn4[hx].z:kn4[hx].w;
          float arg = fminf(fmaf(TWO_LOG2E, acc[r], qnL + knv), 0.f);
          float e1  = exp2f(arg);                     // e^{-d2}
          float y   = fmaf(-SCALE, e1, SCALE);        // in [0, 0.125]
          float tt  = fmaf(0.5f, y, 1.0f);
          float wv  = fmaf(y, tt, 1.0f);              // exp(y) 2nd-order poly
          if (MASK) {
            const int sof = 32*(hx>>1) + 8*lg + 4*(hx&1);
            wv = (s_base + sof + r <= l_glob) ? wv : 0.f;
          }
          den += wv;
          wv4[r] = wv;
        }
        up[hx][0] = pack_bf16(wv4[0], wv4[1]);
        up[hx][1] = pack_bf16(wv4[2], wv4[3]);
      }
      // ---- PV: P lane-local; V fragments direct from global (L2-resident) ----
      #pragma unroll
      for (int sc = 0; sc < 2; ++sc) {
        union { unsigned u[4]; bf16x8 vv; } pb;
        pb.u[0] = up[2*sc][0];
        pb.u[1] = up[2*sc][1];
        pb.u[2] = up[2*sc+1][0];
        pb.u[3] = up[2*sc+1][1];
        const bf16x8 pf = pb.vv;
        #pragma unroll
        for (int dsb = 0; dsb < 4; ++dsb) {
          const __bf16* vp = Vh + (size_t)(dsb*16 + lr) * L + s_base + sc*32 + lg*8;
          const bf16x8 vf = *reinterpret_cast<const bf16x8*>(vp);
          oacc[dsb] = __builtin_amdgcn_mfma_f32_16x16x32_bf16(pf, vf, oacc[dsb], 0, 0, 0);
        }
      }
      __builtin_amdgcn_s_setprio(0);
    };

    const int n_it = ((lt - j) >> 2) + 1;
    loadK(j);
    writeK();
    __syncthreads();
    for (int i = 0; i < n_it; ++i) {
      const int c = 4 * i + j;
      const bool more = (i + 1 < n_it);
      if (more) loadK(c + 4);              // prefetch to regs
      compute(c, c == lt);
      if (more) {
        __syncthreads();                   // all waves done reading
        writeK();
        __syncthreads();                   // staged data visible
      }
    }
  }

  // ---- den: reduce over lg (per l = lr) ----
  den += __shfl_xor(den, 16);
  den += __shfl_xor(den, 32);

  // ---- write partials (all blocks, including empty slices -> zeros) ----
  {
    float* pb = Pp + ((size_t)(j * 16 + n) * L + (l0 + 16 * w4)) * 64;
    #pragma unroll
    for (int r = 0; r < 4; ++r) {
      float* prow = pb + (size_t)(4*lg + r) * 64;
      #pragma unroll
      for (int dsb = 0; dsb < 4; ++dsb)
        prow[dsb*16 + lr] = oacc[dsb][r];
    }
    if (lane < 16)
      Dp[(size_t)(j * 16 + n) * L + l0 + 16 * w4 + lr] = den;
  }
}

// ---- merge: O = (sum_j P_j) / (sum_j den_j), normalized, final layout ----
__global__ __launch_bounds__(256)
void merge(const float* __restrict__ Pp, const float* __restrict__ Dp,
           float* __restrict__ Og) {
  const int gid = blockIdx.x * 256 + threadIdx.x;   // 0 .. 524287 (float4 units)
  const int nq = gid >> 4, d4 = gid & 15;
  const int n = nq >> 11, q = nq & 2047;
  const float4* P4 = reinterpret_cast<const float4*>(Pp);
  float sx = 0.f, sy = 0.f, sz = 0.f, sw = 0.f, den = 0.f;
  #pragma unroll
  for (int jj = 0; jj < 4; ++jj) {
    const float4 p = P4[((size_t)(jj << 15) + nq) * 16 + d4];
    sx += p.x; sy += p.y; sz += p.z; sw += p.w;
    den += Dp[(size_t)(jj << 15) + nq];
  }
  const float inv = 1.0f / den;
  float4 o; o.x = sx * inv; o.y = sy * inv; o.z = sz * inv; o.w = sw * inv;
  float* op = Og + ((size_t)(n >> 3) * L + q) * 512 + (n & 7) * 64 + d4 * 4;
  *reinterpret_cast<float4*>(op) = o;
}

} // namespace

extern "C" void kernel_launch(void* const* d_in, const int* in_sizes, int n_in,
                              void* d_out, int out_size, void* d_ws, size_t ws_size,
                              hipStream_t stream) {
  (void)in_sizes; (void)n_in; (void)out_size; (void)ws_size;
  const float* q = (const float*)d_in[0];
  const float* k = (const float*)d_in[1];
  const float* v = (const float*)d_in[2];
  float*       o = (float*)d_out;

  char* ws = (char*)d_ws;
  float*  kn = (float*)(ws + KN_OFF);
  __bf16* Kb = (__bf16*)(ws + KB_OFF);
  __bf16* Vt = (__bf16*)(ws + VT_OFF);
  float*  Pp = (float*)(ws + P_OFF);
  float*  Dp = (float*)(ws + D_OFF);

  prep<<<dim3(1024), dim3(256), 0, stream>>>(k, v, Kb, kn, Vt);
  degr_attn<<<dim3(2048), dim3(256), 0, stream>>>(q, Kb, Vt, kn, Pp, Dp);
  merge<<<dim3(2048), dim3(256), 0, stream>>>(Pp, Dp, o);
}

// Round 13
// 68.316 us; speedup vs baseline: 1.8020x; 1.0195x over previous
//
#include <hip/hip_runtime.h>
#include <hip/hip_bf16.h>

typedef __attribute__((ext_vector_type(8))) __bf16 bf16x8;
typedef __attribute__((ext_vector_type(4))) float f32x4;

namespace {

constexpr int L = 2048;      // query length (== S)
constexpr int E = 64;        // embed dim == value dim
constexpr int NHEAD = 16;    // B*H reinterpreted heads
constexpr float SCALE = 0.125f;   // 1/sqrt(64)
constexpr float LOG2E = 1.44269504f;
constexpr float TWO_LOG2E = 2.88539008f;

// workspace layout (bytes)
constexpr size_t KN_OFF = 4096;                               // f32 [16][2048]  (-log2e*|k|^2)
constexpr size_t KB_OFF = KN_OFF + (size_t)NHEAD * L * 4;     // bf16 [16][2048][64]
constexpr size_t VT_OFF = KB_OFF + (size_t)NHEAD * L * E * 2; // bf16 [16][64][2048]
constexpr size_t P_OFF  = VT_OFF + (size_t)NHEAD * E * L * 2; // f32 [4][16][2048][64] partials
constexpr size_t D_OFF  = P_OFF + (size_t)4 * NHEAD * L * E * 4; // f32 [4][16][2048]

// XOR swizzle within a 128-byte LDS row (verified low-conflict rounds 5-12)
__device__ __forceinline__ int swz(int row, int byte_in_row) {
  const int f = (row & 3) | (((row >> 3) & 1) << 2);
  return row * 128 + (byte_in_row ^ (f << 4));
}

__device__ __forceinline__ unsigned pack_bf16(float a, float b) {
  union { __bf16 h[2]; unsigned u; } p;
  p.h[0] = (__bf16)a; p.h[1] = (__bf16)b;
  return p.u;
}

__device__ __forceinline__ void cvt_row16(const float4* src, float& pn,
                                          bf16x8& w0, bf16x8& w1) {
  float4 a = src[0], c = src[1];
  pn += a.x*a.x + a.y*a.y + a.z*a.z + a.w*a.w;
  pn += c.x*c.x + c.y*c.y + c.z*c.z + c.w*c.w;
  w0[0]=(__bf16)a.x; w0[1]=(__bf16)a.y; w0[2]=(__bf16)a.z; w0[3]=(__bf16)a.w;
  w0[4]=(__bf16)c.x; w0[5]=(__bf16)c.y; w0[6]=(__bf16)c.z; w0[7]=(__bf16)c.w;
  float4 d = src[2], e = src[3];
  pn += d.x*d.x + d.y*d.y + d.z*d.z + d.w*d.w;
  pn += e.x*e.x + e.y*e.y + e.z*e.z + e.w*e.w;
  w1[0]=(__bf16)d.x; w1[1]=(__bf16)d.y; w1[2]=(__bf16)d.z; w1[3]=(__bf16)d.w;
  w1[4]=(__bf16)e.x; w1[5]=(__bf16)e.y; w1[6]=(__bf16)e.z; w1[7]=(__bf16)e.w;
}

// merged prep: blocks [0,512) convert K -> bf16 + scaled norms; [512,1024) transpose V
__global__ __launch_bounds__(256)
void prep(const float* __restrict__ Kg, const float* __restrict__ Vg,
          __bf16* __restrict__ Kb, float* __restrict__ kn,
          __bf16* __restrict__ Vt) {
  __shared__ float Vs[64][65];
  const int t = threadIdx.x;
  if (blockIdx.x < 512) {
    const int row = blockIdx.x * 64 + (t >> 2);
    const int seg = t & 3;
    const float4* src = reinterpret_cast<const float4*>(
        Kg + (size_t)row * E + seg * 16);
    float pn = 0.f; bf16x8 w0, w1;
    cvt_row16(src, pn, w0, w1);
    __bf16* dst = Kb + (size_t)row * E + seg * 16;
    *reinterpret_cast<bf16x8*>(dst)     = w0;
    *reinterpret_cast<bf16x8*>(dst + 8) = w1;
    pn += __shfl_xor(pn, 1);
    pn += __shfl_xor(pn, 2);
    if (seg == 0) kn[row] = -LOG2E * pn;      // pre-scaled
  } else {
    const int bb = blockIdx.x - 512;
    const int n  = bb >> 5;    // head 0..15
    const int st = bb & 31;    // s-tile of 64
    const int b = n >> 3, h = n & 7;
    {
      const int srow = t >> 2, seg = t & 3;
      const float4* src = reinterpret_cast<const float4*>(
          Vg + ((size_t)b * L + st * 64 + srow) * 512 + h * 64 + seg * 16);
      #pragma unroll
      for (int jj = 0; jj < 4; ++jj) {
        float4 a = src[jj];
        Vs[srow][seg*16 + jj*4 + 0] = a.x;
        Vs[srow][seg*16 + jj*4 + 1] = a.y;
        Vs[srow][seg*16 + jj*4 + 2] = a.z;
        Vs[srow][seg*16 + jj*4 + 3] = a.w;
      }
    }
    __syncthreads();
    {
      const int d = t >> 2, sg = t & 3;
      bf16x8 o0, o1;
      #pragma unroll
      for (int i = 0; i < 8; ++i) o0[i] = (__bf16)Vs[sg*16 + i][d];
      #pragma unroll
      for (int i = 0; i < 8; ++i) o1[i] = (__bf16)Vs[sg*16 + 8 + i][d];
      __bf16* dst = Vt + (size_t)n * (E * L) + (size_t)d * L + st * 64 + sg * 16;
      *reinterpret_cast<bf16x8*>(dst)     = o0;
      *reinterpret_cast<bf16x8*>(dst + 8) = o1;
    }
  }
}

// ---- main attention: 1024 blocks x 4 waves; each wave owns 32 q-rows
// (two 16-row subtiles A/B sharing kf/kn/vf/staging). Block = (head n,
// 128-row l-tile lt, s-slice j); chunks c == j (mod 4), c <= 2*lt+1.
// f32 partials to workspace; merge kernel combines the 4 slices.
// NOTE: min-waves must stay <= 4 (128-VGPR cap): 64-cap spills 260MB (r10/r11).
__global__ __launch_bounds__(256, 4)
void degr_attn(const float* __restrict__ Qg, const __bf16* __restrict__ Kb,
               const __bf16* __restrict__ Vt, const float* __restrict__ kng,
               float* __restrict__ Pp, float* __restrict__ Dp) {
  __shared__ char smem[8192];    // K tile, swizzled, single-buffered

  const int id = blockIdx.x;
  const int n  = id & 15;                       // 2 heads per XCD
  const int v  = id >> 4;                       // 0..63
  const int w  = v & 15, k = v >> 4;            // k = slice j
  const int lt = (k < 2) ? w : (15 - w);        // pair (w, 15-w) per CU
  const int j  = k;
  const int l0 = lt * 128;
  const int cmax = 2 * lt + 1;

  const int t = threadIdx.x;
  const int w4 = t >> 6;                        // wave 0..3
  const int lane = t & 63, lg = lane >> 4, lr = lane & 15;

  f32x4 oA[4], oB[4];
  #pragma unroll
  for (int i = 0; i < 4; ++i) {
    oA[i] = (f32x4){0.f, 0.f, 0.f, 0.f};
    oB[i] = (f32x4){0.f, 0.f, 0.f, 0.f};
  }
  float denA = 0.f, denB = 0.f;

  const int lA = l0 + 32 * w4 + lr;             // subtile A row
  const int lB = lA + 16;                       // subtile B row

  if (j <= cmax) {
    const float*  Qh  = Qg  + (size_t)n * (L * E);
    const __bf16* Kh  = Kb  + (size_t)n * (L * E);
    const __bf16* Vh  = Vt  + (size_t)n * (E * L);
    const float*  knh = kng + (size_t)n * L;

    // ---- Q fragments for both subtiles + lane-local scaled norms ----
    bf16x8 qA0, qA1, qB0, qB1;
    float qnA, qnB;
    auto loadQ = [&](int lglob, bf16x8& f0, bf16x8& f1, float& qn) {
      const float* qp = Qh + (size_t)lglob * E + 8 * lg;
      float4 a  = *reinterpret_cast<const float4*>(qp);
      float4 d  = *reinterpret_cast<const float4*>(qp + 4);
      float4 a2 = *reinterpret_cast<const float4*>(qp + 32);
      float4 d2 = *reinterpret_cast<const float4*>(qp + 36);
      float pn = 0.f;
      #pragma unroll
      for (int i = 0; i < 4; ++i) {
        float v0 = (i==0)?a.x:(i==1)?a.y:(i==2)?a.z:a.w;
        float v1 = (i==0)?d.x:(i==1)?d.y:(i==2)?d.z:d.w;
        float v2 = (i==0)?a2.x:(i==1)?a2.y:(i==2)?a2.z:a2.w;
        float v3 = (i==0)?d2.x:(i==1)?d2.y:(i==2)?d2.z:d2.w;
        f0[i]   = (__bf16)v0;  f0[i+4] = (__bf16)v1;
        f1[i]   = (__bf16)v2;  f1[i+4] = (__bf16)v3;
        float f;
        f = (float)f0[i];   pn += f*f;
        f = (float)f0[i+4]; pn += f*f;
        f = (float)f1[i];   pn += f*f;
        f = (float)f1[i+4]; pn += f*f;
      }
      pn += __shfl_xor(pn, 16);
      pn += __shfl_xor(pn, 32);
      qn = -LOG2E * pn;
    };
    loadQ(lA, qA0, qA1, qnA);
    loadQ(lB, qB0, qB1, qnB);

    // ---- precomputed LDS offsets (K only) ----
    const int srow = t >> 2;
    const int scol = (t & 3) * 2;
    const int wk0 = swz(srow, scol*16);
    const int wk1 = swz(srow, scol*16 + 16);
    int koffL[4], koffH[4];
    #pragma unroll
    for (int hx = 0; hx < 4; ++hx) {
      const int krow = 32*(hx>>1) + 8*(lr>>2) + 4*(hx&1) + (lr&3);
      koffL[hx] = swz(krow, lg*16);
      koffH[hx] = swz(krow, 64 + lg*16);
    }

    bf16x8 kr0, kr1;
    auto loadK = [&](int c) {
      const __bf16* kp = Kh + (size_t)(c * 64 + srow) * E + scol * 8;
      kr0 = *reinterpret_cast<const bf16x8*>(kp);
      kr1 = *reinterpret_cast<const bf16x8*>(kp + 8);
    };
    auto writeK = [&]() {
      *reinterpret_cast<bf16x8*>(smem + wk0) = kr0;
      *reinterpret_cast<bf16x8*>(smem + wk1) = kr1;
    };

    auto compute = [&](int c, bool MASK) {
      const int s_base = c * 64;
      float4 kn4[4];
      kn4[0] = *reinterpret_cast<const float4*>(knh + s_base + 8*lg);
      kn4[1] = *reinterpret_cast<const float4*>(knh + s_base + 8*lg + 4);
      kn4[2] = *reinterpret_cast<const float4*>(knh + s_base + 32 + 8*lg);
      kn4[3] = *reinterpret_cast<const float4*>(knh + s_base + 36 + 8*lg);

      __builtin_amdgcn_s_setprio(1);
      unsigned upA[4][2], upB[4][2];
      #pragma unroll
      for (int hx = 0; hx < 4; ++hx) {
        const bf16x8 kf0 = *reinterpret_cast<const bf16x8*>(smem + koffL[hx]);
        const bf16x8 kf1 = *reinterpret_cast<const bf16x8*>(smem + koffH[hx]);
        f32x4 aA = (f32x4){0.f, 0.f, 0.f, 0.f};
        f32x4 aB = (f32x4){0.f, 0.f, 0.f, 0.f};
        aA = __builtin_amdgcn_mfma_f32_16x16x32_bf16(kf0, qA0, aA, 0, 0, 0);
        aA = __builtin_amdgcn_mfma_f32_16x16x32_bf16(kf1, qA1, aA, 0, 0, 0);
        aB = __builtin_amdgcn_mfma_f32_16x16x32_bf16(kf0, qB0, aB, 0, 0, 0);
        aB = __builtin_amdgcn_mfma_f32_16x16x32_bf16(kf1, qB1, aB, 0, 0, 0);
        const int sof = 32*(hx>>1) + 8*lg + 4*(hx&1);   // s-local for r=0
        float wA[4], wB[4];
        #pragma unroll
        for (int r = 0; r < 4; ++r) {
          const float knv = (r==0)?kn4[hx].x:(r==1)?kn4[hx].y:(r==2)?kn4[hx].z:kn4[hx].w;
          // raw v_exp_f32: arg in [-370, 0], underflows to 0 correctly
          float argA = fminf(fmaf(TWO_LOG2E, aA[r], qnA + knv), 0.f);
          float argB = fminf(fmaf(TWO_LOG2E, aB[r], qnB + knv), 0.f);
          float e1A  = __builtin_amdgcn_exp2f(argA);
          float e1B  = __builtin_amdgcn_exp2f(argB);
          float yA   = fmaf(-SCALE, e1A, SCALE);
          float yB   = fmaf(-SCALE, e1B, SCALE);
          float wvA  = fmaf(yA, fmaf(0.5f, yA, 1.0f), 1.0f);   // exp(y) poly
          float wvB  = fmaf(yB, fmaf(0.5f, yB, 1.0f), 1.0f);
          if (MASK) {
            const int s_glob = s_base + sof + r;
            wvA = (s_glob <= lA) ? wvA : 0.f;
            wvB = (s_glob <= lB) ? wvB : 0.f;
          }
          denA += wvA;  denB += wvB;
          wA[r] = wvA;  wB[r] = wvB;
        }
        upA[hx][0] = pack_bf16(wA[0], wA[1]);
        upA[hx][1] = pack_bf16(wA[2], wA[3]);
        upB[hx][0] = pack_bf16(wB[0], wB[1]);
        upB[hx][1] = pack_bf16(wB[2], wB[3]);
      }
      // ---- PV: P lane-local; V fragment shared by both subtiles ----
      #pragma unroll
      for (int sc = 0; sc < 2; ++sc) {
        union { unsigned u[4]; bf16x8 vv; } pa, pb;
        pa.u[0] = upA[2*sc][0]; pa.u[1] = upA[2*sc][1];
        pa.u[2] = upA[2*sc+1][0]; pa.u[3] = upA[2*sc+1][1];
        pb.u[0] = upB[2*sc][0]; pb.u[1] = upB[2*sc][1];
        pb.u[2] = upB[2*sc+1][0]; pb.u[3] = upB[2*sc+1][1];
        #pragma unroll
        for (int dsb = 0; dsb < 4; ++dsb) {
          const __bf16* vp = Vh + (size_t)(dsb*16 + lr) * L + s_base + sc*32 + lg*8;
          const bf16x8 vf = *reinterpret_cast<const bf16x8*>(vp);
          oA[dsb] = __builtin_amdgcn_mfma_f32_16x16x32_bf16(pa.vv, vf, oA[dsb], 0, 0, 0);
          oB[dsb] = __builtin_amdgcn_mfma_f32_16x16x32_bf16(pb.vv, vf, oB[dsb], 0, 0, 0);
        }
      }
      __builtin_amdgcn_s_setprio(0);
    };

    const int n_it = ((cmax - j) >> 2) + 1;
    loadK(j);
    writeK();
    __syncthreads();
    for (int i = 0; i < n_it; ++i) {
      const int c = 4 * i + j;
      const bool more = (i + 1 < n_it);
      if (more) loadK(c + 4);              // prefetch to regs
      compute(c, c >= 2 * lt);             // only top two chunks need masking
      if (more) {
        __syncthreads();                   // all waves done reading
        writeK();
        __syncthreads();                   // staged data visible
      }
    }
  }

  // ---- den: reduce over lg (per l = lr within each subtile) ----
  denA += __shfl_xor(denA, 16);
  denA += __shfl_xor(denA, 32);
  denB += __shfl_xor(denB, 16);
  denB += __shfl_xor(denB, 32);

  // ---- write partials (all blocks; empty slices write zeros) ----
  {
    const int rowA = l0 + 32 * w4;
    float* pbA = Pp + ((size_t)(j * 16 + n) * L + rowA) * 64;
    float* pbB = pbA + (size_t)16 * 64;
    #pragma unroll
    for (int r = 0; r < 4; ++r) {
      float* prA = pbA + (size_t)(4*lg + r) * 64;
      float* prB = pbB + (size_t)(4*lg + r) * 64;
      #pragma unroll
      for (int dsb = 0; dsb < 4; ++dsb) {
        prA[dsb*16 + lr] = oA[dsb][r];
        prB[dsb*16 + lr] = oB[dsb][r];
      }
    }
    if (lane < 16) {
      Dp[(size_t)(j * 16 + n) * L + rowA + lr]      = denA;
      Dp[(size_t)(j * 16 + n) * L + rowA + 16 + lr] = denB;
    }
  }
}

// ---- merge: O = (sum_j P_j) / (sum_j den_j), normalized, final layout ----
__global__ __launch_bounds__(256)
void merge(const float* __restrict__ Pp, const float* __restrict__ Dp,
           float* __restrict__ Og) {
  const int gid = blockIdx.x * 256 + threadIdx.x;   // 0 .. 524287 (float4 units)
  const int nq = gid >> 4, d4 = gid & 15;
  const int n = nq >> 11, q = nq & 2047;
  const float4* P4 = reinterpret_cast<const float4*>(Pp);
  float sx = 0.f, sy = 0.f, sz = 0.f, sw = 0.f, den = 0.f;
  #pragma unroll
  for (int jj = 0; jj < 4; ++jj) {
    const float4 p = P4[((size_t)(jj << 15) + nq) * 16 + d4];
    sx += p.x; sy += p.y; sz += p.z; sw += p.w;
    den += Dp[(size_t)(jj << 15) + nq];
  }
  const float inv = 1.0f / den;
  float4 o; o.x = sx * inv; o.y = sy * inv; o.z = sz * inv; o.w = sw * inv;
  float* op = Og + ((size_t)(n >> 3) * L + q) * 512 + (n & 7) * 64 + d4 * 4;
  *reinterpret_cast<float4*>(op) = o;
}

} // namespace

extern "C" void kernel_launch(void* const* d_in, const int* in_sizes, int n_in,
                              void* d_out, int out_size, void* d_ws, size_t ws_size,
                              hipStream_t stream) {
  (void)in_sizes; (void)n_in; (void)out_size; (void)ws_size;
  const float* q = (const float*)d_in[0];
  const float* k = (const float*)d_in[1];
  const float* v = (const float*)d_in[2];
  float*       o = (float*)d_out;

  char* ws = (char*)d_ws;
  float*  kn = (float*)(ws + KN_OFF);
  __bf16* Kb = (__bf16*)(ws + KB_OFF);
  __bf16* Vt = (__bf16*)(ws + VT_OFF);
  float*  Pp = (float*)(ws + P_OFF);
  float*  Dp = (float*)(ws + D_OFF);

  prep<<<dim3(1024), dim3(256), 0, stream>>>(k, v, Kb, kn, Vt);
  degr_attn<<<dim3(1024), dim3(256), 0, stream>>>(q, Kb, Vt, kn, Pp, Dp);
  merge<<<dim3(2048), dim3(256), 0, stream>>>(Pp, Dp, o);
}

// Round 14
// 48.303 us; speedup vs baseline: 2.5486x; 1.4143x over previous
//
#include <hip/hip_runtime.h>
#include <hip/hip_bf16.h>

typedef __attribute__((ext_vector_type(8))) __bf16 bf16x8;
typedef __attribute__((ext_vector_type(4))) float f32x4;

namespace {

constexpr int L = 2048;      // query length (== S)
constexpr int E = 64;        // embed dim == value dim
constexpr int NHEAD = 16;    // B*H reinterpreted heads
constexpr float SCALE = 0.125f;   // 1/sqrt(64)
constexpr float LOG2E = 1.44269504f;
constexpr float TWO_LOG2E = 2.88539008f;

// workspace layout (bytes)
constexpr size_t KN_OFF = 4096;                               // f32 [16][2048]  (-log2e*|k|^2)
constexpr size_t KB_OFF = KN_OFF + (size_t)NHEAD * L * 4;     // bf16 [16][2048][64]
constexpr size_t VT_OFF = KB_OFF + (size_t)NHEAD * L * E * 2; // bf16 [16][64][2048]
constexpr size_t P_OFF  = VT_OFF + (size_t)NHEAD * E * L * 2; // f32 [2][16][2048][64] partials
constexpr size_t D_OFF  = P_OFF + (size_t)2 * NHEAD * L * E * 4; // f32 [2][16][2048]

// XOR swizzle within a 128-byte LDS row (verified low-conflict rounds 5-13)
__device__ __forceinline__ int swz(int row, int byte_in_row) {
  const int f = (row & 3) | (((row >> 3) & 1) << 2);
  return row * 128 + (byte_in_row ^ (f << 4));
}

__device__ __forceinline__ unsigned pack_bf16(float a, float b) {
  union { __bf16 h[2]; unsigned u; } p;
  p.h[0] = (__bf16)a; p.h[1] = (__bf16)b;
  return p.u;
}

__device__ __forceinline__ void cvt_row16(const float4* src, float& pn,
                                          bf16x8& w0, bf16x8& w1) {
  float4 a = src[0], c = src[1];
  pn += a.x*a.x + a.y*a.y + a.z*a.z + a.w*a.w;
  pn += c.x*c.x + c.y*c.y + c.z*c.z + c.w*c.w;
  w0[0]=(__bf16)a.x; w0[1]=(__bf16)a.y; w0[2]=(__bf16)a.z; w0[3]=(__bf16)a.w;
  w0[4]=(__bf16)c.x; w0[5]=(__bf16)c.y; w0[6]=(__bf16)c.z; w0[7]=(__bf16)c.w;
  float4 d = src[2], e = src[3];
  pn += d.x*d.x + d.y*d.y + d.z*d.z + d.w*d.w;
  pn += e.x*e.x + e.y*e.y + e.z*e.z + e.w*e.w;
  w1[0]=(__bf16)d.x; w1[1]=(__bf16)d.y; w1[2]=(__bf16)d.z; w1[3]=(__bf16)d.w;
  w1[4]=(__bf16)e.x; w1[5]=(__bf16)e.y; w1[6]=(__bf16)e.z; w1[7]=(__bf16)e.w;
}

// merged prep: blocks [0,512) convert K -> bf16 + scaled norms; [512,1024) transpose V
__global__ __launch_bounds__(256)
void prep(const float* __restrict__ Kg, const float* __restrict__ Vg,
          __bf16* __restrict__ Kb, float* __restrict__ kn,
          __bf16* __restrict__ Vt) {
  __shared__ float Vs[64][65];
  const int t = threadIdx.x;
  if (blockIdx.x < 512) {
    const int row = blockIdx.x * 64 + (t >> 2);
    const int seg = t & 3;
    const float4* src = reinterpret_cast<const float4*>(
        Kg + (size_t)row * E + seg * 16);
    float pn = 0.f; bf16x8 w0, w1;
    cvt_row16(src, pn, w0, w1);
    __bf16* dst = Kb + (size_t)row * E + seg * 16;
    *reinterpret_cast<bf16x8*>(dst)     = w0;
    *reinterpret_cast<bf16x8*>(dst + 8) = w1;
    pn += __shfl_xor(pn, 1);
    pn += __shfl_xor(pn, 2);
    if (seg == 0) kn[row] = -LOG2E * pn;      // pre-scaled
  } else {
    const int bb = blockIdx.x - 512;
    const int n  = bb >> 5;    // head 0..15
    const int st = bb & 31;    // s-tile of 64
    const int b = n >> 3, h = n & 7;
    {
      const int srow = t >> 2, seg = t & 3;
      const float4* src = reinterpret_cast<const float4*>(
          Vg + ((size_t)b * L + st * 64 + srow) * 512 + h * 64 + seg * 16);
      #pragma unroll
      for (int jj = 0; jj < 4; ++jj) {
        float4 a = src[jj];
        Vs[srow][seg*16 + jj*4 + 0] = a.x;
        Vs[srow][seg*16 + jj*4 + 1] = a.y;
        Vs[srow][seg*16 + jj*4 + 2] = a.z;
        Vs[srow][seg*16 + jj*4 + 3] = a.w;
      }
    }
    __syncthreads();
    {
      const int d = t >> 2, sg = t & 3;
      bf16x8 o0, o1;
      #pragma unroll
      for (int i = 0; i < 8; ++i) o0[i] = (__bf16)Vs[sg*16 + i][d];
      #pragma unroll
      for (int i = 0; i < 8; ++i) o1[i] = (__bf16)Vs[sg*16 + 8 + i][d];
      __bf16* dst = Vt + (size_t)n * (E * L) + (size_t)d * L + st * 64 + sg * 16;
      *reinterpret_cast<bf16x8*>(dst)     = o0;
      *reinterpret_cast<bf16x8*>(dst + 8) = o1;
    }
  }
}

// ---- main attention: 1024 blocks x 8 waves = 2 groups x 4 waves.
// Block = (head n, 64-row l-tile lt, s-slice jb); group g handles chunks
// c == jb + 2g (mod 4), c <= lt. K+V staged in group-private LDS (16KB,
// single-buffered, reg-carry prefetch). f32 slice-partials; merge combines.
// NOTE: keep min-waves at 4 (cap 128): forcing 8 spills ~35MB (r10/11/13).
__global__ __launch_bounds__(512, 4)
void degr_attn(const float* __restrict__ Qg, const __bf16* __restrict__ Kb,
               const __bf16* __restrict__ Vt, const float* __restrict__ kng,
               float* __restrict__ Pp, float* __restrict__ Dp) {
  __shared__ char smem[32768];
  // staging: group g: K @ g*16384, V @ g*16384+8192
  // epilogue overlay: Cbuf 64x65 f32 @0, Dbuf 64 f32 @17408

  const int id = blockIdx.x;
  const int n  = id & 15;                        // heads n, n+8 share an XCD
  const int v  = id >> 4;                        // 0..63
  const int w  = v & 15, k = v >> 4;             // k in 0..3
  const int lt = (k & 1) ? (31 - w) : w;
  const int jb = k >> 1;                         // block s-slice 0/1
  const int l0 = lt * 64;

  const int t = threadIdx.x;
  const int wave = t >> 6, grp = wave >> 2, w4 = wave & 3;
  const int lane = t & 63, lg = lane >> 4, lr = lane & 15;
  const int gt = t & 255;   // group-local thread

  char* kbase = smem + grp * 16384;
  char* vbase = kbase + 8192;
  float* Cbuf = (float*)smem;                    // overlay (after loop)
  float* Dbuf = (float*)(smem + 17408);

  const float*  Qh  = Qg  + (size_t)n * (L * E);
  const __bf16* Kh  = Kb  + (size_t)n * (L * E);
  const __bf16* Vh  = Vt  + (size_t)n * (E * L);
  const float*  knh = kng + (size_t)n * L;

  // ---- Q fragments direct from global (f32 -> bf16 in regs) + lane-local qn ----
  const int l_glob = l0 + 16 * w4 + lr;
  bf16x8 qf0, qf1;
  float qnL;
  {
    const float* qp = Qh + (size_t)l_glob * E + 8 * lg;
    float4 a = *reinterpret_cast<const float4*>(qp);
    float4 d = *reinterpret_cast<const float4*>(qp + 4);
    float4 a2 = *reinterpret_cast<const float4*>(qp + 32);
    float4 d2v = *reinterpret_cast<const float4*>(qp + 36);
    float pn = 0.f;
    #pragma unroll
    for (int i = 0; i < 4; ++i) {
      float v0 = (i==0)?a.x:(i==1)?a.y:(i==2)?a.z:a.w;
      float v1 = (i==0)?d.x:(i==1)?d.y:(i==2)?d.z:d.w;
      float v2 = (i==0)?a2.x:(i==1)?a2.y:(i==2)?a2.z:a2.w;
      float v3 = (i==0)?d2v.x:(i==1)?d2v.y:(i==2)?d2v.z:d2v.w;
      qf0[i]   = (__bf16)v0;  qf0[i+4] = (__bf16)v1;
      qf1[i]   = (__bf16)v2;  qf1[i+4] = (__bf16)v3;
      float f;
      f = (float)qf0[i];   pn += f*f;
      f = (float)qf0[i+4]; pn += f*f;
      f = (float)qf1[i];   pn += f*f;
      f = (float)qf1[i+4]; pn += f*f;
    }
    pn += __shfl_xor(pn, 16);
    pn += __shfl_xor(pn, 32);
    qnL = -LOG2E * pn;       // pre-scaled |q|^2
  }

  // ---- precomputed LDS offsets ----
  const int srow = gt >> 2;
  const int scol = (gt & 3) * 2;
  const int wk0 = swz(srow, scol*16);
  const int wk1 = swz(srow, scol*16 + 16);
  int koffL[4], koffH[4];
  #pragma unroll
  for (int hx = 0; hx < 4; ++hx) {
    const int krow = 32*(hx>>1) + 8*(lr>>2) + 4*(hx&1) + (lr&3);
    koffL[hx] = swz(krow, lg*16);
    koffH[hx] = swz(krow, 64 + lg*16);
  }
  int voff[2][4];
  #pragma unroll
  for (int sc = 0; sc < 2; ++sc)
    #pragma unroll
    for (int dsb = 0; dsb < 4; ++dsb)
      voff[sc][dsb] = swz(dsb*16 + lr, sc*64 + lg*16);

  bf16x8 kr0, kr1, vr0, vr1;
  auto loadKV = [&](int c) {
    const int s0 = c * 64;
    const __bf16* kp = Kh + (size_t)(s0 + srow) * E + scol * 8;
    kr0 = *reinterpret_cast<const bf16x8*>(kp);
    kr1 = *reinterpret_cast<const bf16x8*>(kp + 8);
    const __bf16* vp = Vh + (size_t)srow * L + s0 + scol * 8;
    vr0 = *reinterpret_cast<const bf16x8*>(vp);
    vr1 = *reinterpret_cast<const bf16x8*>(vp + 8);
  };
  auto writeKV = [&]() {
    *reinterpret_cast<bf16x8*>(kbase + wk0) = kr0;
    *reinterpret_cast<bf16x8*>(kbase + wk1) = kr1;
    *reinterpret_cast<bf16x8*>(vbase + wk0) = vr0;
    *reinterpret_cast<bf16x8*>(vbase + wk1) = vr1;
  };

  f32x4 oacc[4];
  #pragma unroll
  for (int i = 0; i < 4; ++i) oacc[i] = (f32x4){0.f, 0.f, 0.f, 0.f};
  float den = 0.f;

  auto compute = [&](int c, bool MASK) {
    const int s_base = c * 64;
    float4 kn4[4];
    kn4[0] = *reinterpret_cast<const float4*>(knh + s_base + 8*lg);
    kn4[1] = *reinterpret_cast<const float4*>(knh + s_base + 8*lg + 4);
    kn4[2] = *reinterpret_cast<const float4*>(knh + s_base + 32 + 8*lg);
    kn4[3] = *reinterpret_cast<const float4*>(knh + s_base + 36 + 8*lg);

    __builtin_amdgcn_s_setprio(1);
    unsigned up[4][2];
    #pragma unroll
    for (int hx = 0; hx < 4; ++hx) {
      const bf16x8 kf0 = *reinterpret_cast<const bf16x8*>(kbase + koffL[hx]);
      const bf16x8 kf1 = *reinterpret_cast<const bf16x8*>(kbase + koffH[hx]);
      f32x4 acc = (f32x4){0.f, 0.f, 0.f, 0.f};
      acc = __builtin_amdgcn_mfma_f32_16x16x32_bf16(kf0, qf0, acc, 0, 0, 0);
      acc = __builtin_amdgcn_mfma_f32_16x16x32_bf16(kf1, qf1, acc, 0, 0, 0);
      float wv4[4];
      #pragma unroll
      for (int r = 0; r < 4; ++r) {
        const float knv = (r==0)?kn4[hx].x:(r==1)?kn4[hx].y:(r==2)?kn4[hx].z:kn4[hx].w;
        float arg = fminf(fmaf(TWO_LOG2E, acc[r], qnL + knv), 0.f);
        float e1  = __builtin_amdgcn_exp2f(arg);    // e^{-d2}, raw v_exp_f32
        float y   = fmaf(-SCALE, e1, SCALE);        // in [0, 0.125]
        float wv  = fmaf(y, fmaf(0.5f, y, 1.0f), 1.0f);  // exp(y) poly
        if (MASK) {
          const int sof = 32*(hx>>1) + 8*lg + 4*(hx&1);
          wv = (s_base + sof + r <= l_glob) ? wv : 0.f;
        }
        den += wv;
        wv4[r] = wv;
      }
      up[hx][0] = pack_bf16(wv4[0], wv4[1]);
      up[hx][1] = pack_bf16(wv4[2], wv4[3]);
    }
    #pragma unroll
    for (int sc = 0; sc < 2; ++sc) {
      union { unsigned u[4]; bf16x8 vv; } pb;
      pb.u[0] = up[2*sc][0];
      pb.u[1] = up[2*sc][1];
      pb.u[2] = up[2*sc+1][0];
      pb.u[3] = up[2*sc+1][1];
      const bf16x8 pf = pb.vv;
      #pragma unroll
      for (int dsb = 0; dsb < 4; ++dsb) {
        const bf16x8 vf = *reinterpret_cast<const bf16x8*>(vbase + voff[sc][dsb]);
        oacc[dsb] = __builtin_amdgcn_mfma_f32_16x16x32_bf16(pf, vf, oacc[dsb], 0, 0, 0);
      }
    }
    __builtin_amdgcn_s_setprio(0);
  };

  // ---- chunk loop: group residue c0 = jb + 2*grp, step 4, padded count N ----
  const int N = (lt >= jb) ? ((lt - jb) >> 2) + 1 : 0;
  if (N > 0) {
    const int c0 = jb + 2 * grp;
    loadKV(c0 <= lt ? c0 : lt);
    writeKV();
    __syncthreads();
    for (int i = 0; i < N; ++i) {
      const int c = 4 * i + c0;
      const bool more = (i + 1 < N);
      if (more) {
        int cn = 4 * (i + 1) + c0;
        loadKV(cn <= lt ? cn : lt);        // prefetch to regs (in flight)
      }
      if (c <= lt) compute(c, c == lt);    // pad iterations skip compute
      __syncthreads();                     // group-mates done reading
      if (more) {
        writeKV();
        __syncthreads();                   // staged data visible
      }
    }
  }

  // ---- den: reduce over lg (per l = lr) ----
  den += __shfl_xor(den, 16);
  den += __shfl_xor(den, 32);

  // ---- combine the 2 groups via LDS overlay, write slice partials ----
  if (grp == 1) {
    #pragma unroll
    for (int dsb = 0; dsb < 4; ++dsb)
      #pragma unroll
      for (int r = 0; r < 4; ++r)
        Cbuf[(16*w4 + 4*lg + r) * 65 + 16*dsb + lr] = oacc[dsb][r];
    if (lane < 16) Dbuf[16*w4 + lr] = den;
  }
  __syncthreads();
  if (grp == 0) {
    const float dtot = den + Dbuf[16*w4 + lr];
    float* pb = Pp + ((size_t)(jb * 16 + n) * L + (l0 + 16 * w4)) * 64;
    #pragma unroll
    for (int r = 0; r < 4; ++r) {
      float* prow = pb + (size_t)(4*lg + r) * 64;
      const int ci = (16*w4 + 4*lg + r) * 65 + lr;
      #pragma unroll
      for (int dsb = 0; dsb < 4; ++dsb)
        prow[dsb*16 + lr] = oacc[dsb][r] + Cbuf[ci + 16*dsb];
    }
    if (lane < 16)
      Dp[(size_t)(jb * 16 + n) * L + l0 + 16 * w4 + lr] = dtot;
  }
}

// ---- merge: O = (P_0 + P_1) / (den_0 + den_1), final layout ----
__global__ __launch_bounds__(256)
void merge(const float* __restrict__ Pp, const float* __restrict__ Dp,
           float* __restrict__ Og) {
  const int gid = blockIdx.x * 256 + threadIdx.x;   // 0 .. 524287 (float4 units)
  const int nq = gid >> 4, d4 = gid & 15;
  const int n = nq >> 11, q = nq & 2047;
  const float4* P4 = reinterpret_cast<const float4*>(Pp);
  const float4 p0 = P4[((size_t)nq) * 16 + d4];
  const float4 p1 = P4[((size_t)(1 << 15) + nq) * 16 + d4];
  const float den = Dp[nq] + Dp[(size_t)(1 << 15) + nq];
  const float inv = 1.0f / den;
  float4 o;
  o.x = (p0.x + p1.x) * inv;
  o.y = (p0.y + p1.y) * inv;
  o.z = (p0.z + p1.z) * inv;
  o.w = (p0.w + p1.w) * inv;
  float* op = Og + ((size_t)(n >> 3) * L + q) * 512 + (n & 7) * 64 + d4 * 4;
  *reinterpret_cast<float4*>(op) = o;
}

} // namespace

extern "C" void kernel_launch(void* const* d_in, const int* in_sizes, int n_in,
                              void* d_out, int out_size, void* d_ws, size_t ws_size,
                              hipStream_t stream) {
  (void)in_sizes; (void)n_in; (void)out_size; (void)ws_size;
  const float* q = (const float*)d_in[0];
  const float* k = (const float*)d_in[1];
  const float* v = (const float*)d_in[2];
  float*       o = (float*)d_out;

  char* ws = (char*)d_ws;
  float*  kn = (float*)(ws + KN_OFF);
  __bf16* Kb = (__bf16*)(ws + KB_OFF);
  __bf16* Vt = (__bf16*)(ws + VT_OFF);
  float*  Pp = (float*)(ws + P_OFF);
  float*  Dp = (float*)(ws + D_OFF);

  prep<<<dim3(1024), dim3(256), 0, stream>>>(k, v, Kb, kn, Vt);
  degr_attn<<<dim3(1024), dim3(512), 0, stream>>>(q, Kb, Vt, kn, Pp, Dp);
  merge<<<dim3(2048), dim3(256), 0, stream>>>(Pp, Dp, o);
}